// Round 9
// baseline (403.499 us; speedup 1.0000x reference)
//
#include <hip/hip_runtime.h>

typedef unsigned short ushort_t;
typedef unsigned int uint_t;

typedef short bf16x8 __attribute__((ext_vector_type(8)));
typedef float f32x4 __attribute__((ext_vector_type(4)));

#define MFMA16(a, b, c) __builtin_amdgcn_mfma_f32_16x16x32_bf16(a, b, c, 0, 0, 0)

__device__ __forceinline__ ushort_t f2bf(float f) {
    uint_t u = __float_as_uint(f);
    u += 0x7fffu + ((u >> 16) & 1u);   // RNE
    return (ushort_t)(u >> 16);
}
__device__ __forceinline__ float bf2f(ushort_t h) {
    return __uint_as_float(((uint_t)h) << 16);
}

// ---------------- K0: fused prep. block0: const_h; blocks 1..128: Wa->bf16 blocked;
// blocks 129..144: Ws1[:, :256] -> bf16 hi/lo blocked; blocks 145..208: zero u_i.
// blocked flat (in 8-elem units): ((row/16)*32 + k/8)*16 + row%16
__global__ void k_prep(const float* __restrict__ Ws1, const float* __restrict__ bs1,
                       const float* __restrict__ virt, const float* __restrict__ Wa,
                       float* __restrict__ consth, ushort_t* __restrict__ wa_b,
                       ushort_t* __restrict__ ws1h, ushort_t* __restrict__ ws1l,
                       float* __restrict__ u_i) {
    int b = blockIdx.x;
    if (b == 0) {
        // 2 threads per h-row: tid = half*128 + h
        __shared__ float sred[256];
        int t = threadIdx.x;
        int h = t & 127, half = t >> 7;
        const float* row = Ws1 + h * 512 + 256 + half * 128;
        const float* vv = virt + half * 128;
        float s = 0.f;
#pragma unroll 4
        for (int d = 0; d < 128; ++d) s += row[d] * vv[d];
        sred[t] = s;
        __syncthreads();
        if (t < 128) consth[t] = bs1[t] + sred[t] + sred[t + 128];
        return;
    }
    if (b >= 145) {
        // zero u_i: 64 blocks x 256 threads x 4 floats = 65536
        int t = (b - 145) * 1024 + threadIdx.x * 4;
        float4 z = {0.f, 0.f, 0.f, 0.f};
        *(float4*)(u_i + t) = z;
        return;
    }
    const float* src;
    int src_stride, tid;
    ushort_t *dhi, *dlo;
    if (b <= 128) {
        tid = (b - 1) * 256 + threadIdx.x;   // 1024 rows * 32 = 32768 tids
        src = Wa; src_stride = 256; dhi = wa_b; dlo = nullptr;
    } else {
        tid = (b - 129) * 256 + threadIdx.x; // 128 rows * 32 = 4096 tids
        src = Ws1; src_stride = 512; dhi = ws1h; dlo = ws1l;
    }
    int pl = tid & 15, kc = (tid >> 4) & 31, pt = tid >> 9;
    int row = pt * 16 + pl;
    const float* s = src + (size_t)row * src_stride + kc * 8;
    ushort_t hs[8], ls[8];
#pragma unroll
    for (int j = 0; j < 8; ++j) {
        float v = s[j];
        ushort_t h = f2bf(v);
        hs[j] = h;
        ls[j] = f2bf(v - bf2f(h));
    }
    uint4 hv;
    hv.x = hs[0] | ((uint_t)hs[1] << 16); hv.y = hs[2] | ((uint_t)hs[3] << 16);
    hv.z = hs[4] | ((uint_t)hs[5] << 16); hv.w = hs[6] | ((uint_t)hs[7] << 16);
    *(uint4*)(dhi + (size_t)tid * 8) = hv;
    if (dlo) {
        uint4 lv;
        lv.x = ls[0] | ((uint_t)ls[1] << 16); lv.y = ls[2] | ((uint_t)ls[3] << 16);
        lv.z = ls[4] | ((uint_t)ls[5] << 16); lv.w = ls[6] | ((uint_t)ls[7] << 16);
        *(uint4*)(dlo + (size_t)tid * 8) = lv;
    }
}

// ---------------- K1a: embed (gather+trig) + split-bf16 struct head + sigmoid.
// Writes hi-fragments (blocked, 32 KB/block contiguous) to ghi for K1b, and A_hat.
// (unchanged from R4 — verified)
__global__ __launch_bounds__(256, 2) void k_embed(
    const int* __restrict__ q_seq, const int* __restrict__ r_seq,
    const float* __restrict__ t_seq, const float* __restrict__ q_tab,
    const float* __restrict__ r_tab,
    const ushort_t* __restrict__ ws1h, const ushort_t* __restrict__ ws1l,
    const float* __restrict__ consth, const float* __restrict__ Ws2,
    const float* __restrict__ bs2, const float* __restrict__ mask,
    float* __restrict__ out_ahat, ushort_t* __restrict__ ghi) {
    __shared__ __align__(16) ushort_t sAhi[16384];   // 64 pos x 256 k (hi), 32 KB
    __shared__ __align__(16) ushort_t sAlo[8192];    // 64 pos x 128 k (lo half), 16 KB
    __shared__ float sdiv[128];
    __shared__ float sLogit[64];
    int tid = threadIdx.x;
    if (tid < 128) sdiv[tid] = __expf((float)tid * -0.07195578415606394f); // -ln(10000)/128
    if (tid < 64) sLogit[tid] = 0.0f;
    int w = tid >> 6, lane = tid & 63;
    int pl = lane & 15, kq = lane >> 4;
    int nl = pl;
    int p0 = blockIdx.x * 64;
    int p = p0 + w * 16 + pl;
    int qv = q_seq[p];          // lanes with same pl share qv (same p)
    int rr = r_seq[p];
    float tt = t_seq[p];
    const float* grow = q_tab + (size_t)qv * 256;
    const float* rrow = r_tab + (size_t)rr * 256;
    uint4* gdst = (uint4*)(ghi + (size_t)blockIdx.x * 16384);
    __syncthreads();  // sdiv + sLogit ready
    // ---- gather + trig -> fragments to LDS (MFMA A-layout) + hi copy to global
    uint4 lo_hold[4];
#pragma unroll
    for (int it = 0; it < 8; ++it) {
        int kc = it * 4 + kq;
        int k0 = kc * 8;
        float4 qa = *(const float4*)(grow + kc * 8);
        float4 qb = *(const float4*)(grow + kc * 8 + 4);
        float4 ra = *(const float4*)(rrow + kc * 8);
        float4 rb = *(const float4*)(rrow + kc * 8 + 4);
        float v[8] = {qa.x + ra.x, qa.y + ra.y, qa.z + ra.z, qa.w + ra.w,
                      qb.x + rb.x, qb.y + rb.y, qb.z + rb.z, qb.w + rb.w};
        bool iscos = (kc >= 16);
#pragma unroll
        for (int j = 0; j < 8; ++j) {
            float ang = tt * sdiv[(k0 + j) & 127];
            v[j] += iscos ? __cosf(ang) : __sinf(ang);
        }
        ushort_t hs[8], ls[8];
#pragma unroll
        for (int j = 0; j < 8; ++j) {
            ushort_t h = f2bf(v[j]);
            hs[j] = h;
            ls[j] = (ushort_t)(__float_as_uint(v[j] - bf2f(h)) >> 16);
        }
        uint4 hv, lv;
        hv.x = hs[0] | ((uint_t)hs[1] << 16); hv.y = hs[2] | ((uint_t)hs[3] << 16);
        hv.z = hs[4] | ((uint_t)hs[5] << 16); hv.w = hs[6] | ((uint_t)hs[7] << 16);
        lv.x = ls[0] | ((uint_t)ls[1] << 16); lv.y = ls[2] | ((uint_t)ls[3] << 16);
        lv.z = ls[4] | ((uint_t)ls[5] << 16); lv.w = ls[6] | ((uint_t)ls[7] << 16);
        int unit = (w * 32 + kc) * 16 + pl;
        *(uint4*)(sAhi + unit * 8) = hv;
        gdst[unit] = hv;
        if (it < 4) {
            *(uint4*)(sAlo + ((w * 16 + kc) * 16 + pl) * 8) = lv;   // kc in 0..15
        } else {
            lo_hold[it - 4] = lv;
        }
    }
    __syncthreads();  // fragments visible block-wide
    // ---- struct head (split-bf16, 3 MFMAs), two k-phases over the halved sAlo
    {
        f32x4 acc[4][2];
        f32x4 z4 = {0.f, 0.f, 0.f, 0.f};
#pragma unroll
        for (int mt = 0; mt < 4; ++mt)
#pragma unroll
            for (int nt = 0; nt < 2; ++nt) acc[mt][nt] = z4;
#pragma unroll
        for (int ks = 0; ks < 8; ++ks) {
            if (ks == 4) {
                // swap in the second lo half (barrier: all phase-A sAlo reads done)
                __syncthreads();
#pragma unroll
                for (int it = 4; it < 8; ++it) {
                    int kc = it * 4 + kq;
                    *(uint4*)(sAlo + ((w * 16 + (kc - 16)) * 16 + pl) * 8) = lo_hold[it - 4];
                }
                __syncthreads();
            }
            bf16x8 bh[2], bl[2];
#pragma unroll
            for (int nt = 0; nt < 2; ++nt) {
                int off = (((w * 2 + nt) * 32 + ks * 4 + kq) * 16 + nl) * 8;
                bh[nt] = *(const bf16x8*)(ws1h + off);
                bl[nt] = *(const bf16x8*)(ws1l + off);
            }
#pragma unroll
            for (int mth = 0; mth < 2; ++mth) {
                bf16x8 ahi[2], alo[2];
#pragma unroll
                for (int mi = 0; mi < 2; ++mi) {
                    int mt = mth * 2 + mi;
                    ahi[mi] = *(const bf16x8*)&sAhi[((mt * 32 + ks * 4 + kq) * 16 + nl) * 8];
                    alo[mi] = *(const bf16x8*)&sAlo[((mt * 16 + (ks & 3) * 4 + kq) * 16 + nl) * 8];
                }
#pragma unroll
                for (int mi = 0; mi < 2; ++mi)
#pragma unroll
                    for (int nt = 0; nt < 2; ++nt) {
                        int mt = mth * 2 + mi;
                        acc[mt][nt] = MFMA16(ahi[mi], bh[nt], acc[mt][nt]);
                        acc[mt][nt] = MFMA16(alo[mi], bh[nt], acc[mt][nt]);
                        acc[mt][nt] = MFMA16(ahi[mi], bl[nt], acc[mt][nt]);
                    }
            }
        }
        // epilogue: hdn = leaky(acc + const_h); partial logits = hdn * Ws2
        float ps[4][4];
#pragma unroll
        for (int mt = 0; mt < 4; ++mt)
#pragma unroll
            for (int r = 0; r < 4; ++r) ps[mt][r] = 0.f;
#pragma unroll
        for (int nt = 0; nt < 2; ++nt) {
            int ng = w * 32 + nt * 16 + nl;
            float chv = consth[ng], w2 = Ws2[ng];
#pragma unroll
            for (int mt = 0; mt < 4; ++mt)
#pragma unroll
                for (int r = 0; r < 4; ++r) {
                    float v = acc[mt][nt][r] + chv;
                    v = fmaxf(v, 0.2f * v);
                    ps[mt][r] += v * w2;
                }
        }
#pragma unroll
        for (int mt = 0; mt < 4; ++mt)
#pragma unroll
            for (int r = 0; r < 4; ++r) {
                float x = ps[mt][r];
                x += __shfl_xor(x, 1, 64);
                x += __shfl_xor(x, 2, 64);
                x += __shfl_xor(x, 4, 64);
                x += __shfl_xor(x, 8, 64);
                ps[mt][r] = x;
            }
        if (nl == 0) {
#pragma unroll
            for (int mt = 0; mt < 4; ++mt)
#pragma unroll
                for (int r = 0; r < 4; ++r)
                    atomicAdd(&sLogit[mt * 16 + kq * 4 + r], ps[mt][r]);
        }
    }
    __syncthreads();
    if (tid < 64) {
        int pp = p0 + tid;
        float lg = sLogit[tid] + bs2[0];
        float y = lg * 100.0f;
        y = fminf(fmaxf(y, -60.f), 60.f);
        float a = 1.0f / (1.0f + expf(-y));
        out_ahat[pp] = a * mask[pp];
    }
}

// ---------------- K1b v6: Wa GEMM + aggregator, M=128/block (grid 1024).
// Halves L2 B-traffic (1 GB -> 512 MB, the largest addend in R4's 88.6 µs
// sum-of-pipes) and doubles MFMA per B-issue. Structure = verified R4 loop
// (depth-1 parity B-dbuf, per-ks a_ ds_reads) + inner mh loop sharing each
// streamed B fragment; both halves' accs live (acc[2][4][2] = 64 AGPR).
// R5's spill causes (bfr[8][2] preload) deliberately absent. Arch regs
// ~90-130 + 64 AGPR < 256 cap at (256,2) -> no spill expected.
// Spill sentinel: WRITE_SIZE > 20 MB -> revert to R4-exact k_wa.
__global__ __launch_bounds__(256, 2) void k_wa(
    const ushort_t* __restrict__ ghi, const float* __restrict__ out_ahat,
    const ushort_t* __restrict__ wa_b, const float* __restrict__ ba,
    float* __restrict__ u_i) {
    __shared__ __align__(16) ushort_t sA[32768];   // 128 pos x 256 k (hi), 64 KB
    __shared__ float sAh[128];
    int tid = threadIdx.x;
    int p0 = blockIdx.x * 128;
    // stage A-tiles: 64 KB contiguous (two 64-pos blocked tiles)
    {
        const uint4* src = (const uint4*)(ghi + (size_t)blockIdx.x * 32768);
        uint4* dst = (uint4*)sA;
#pragma unroll 8
        for (int i = 0; i < 16; ++i) dst[tid + i * 256] = src[tid + i * 256];
    }
    if (tid < 128) sAh[tid] = out_ahat[p0 + tid];
    __syncthreads();
    int w = tid >> 6, lane = tid & 63;
    int kq = lane >> 4, nl = lane & 15;
    float ah[2][16];
#pragma unroll
    for (int mh = 0; mh < 2; ++mh)
#pragma unroll
        for (int mt = 0; mt < 4; ++mt)
#pragma unroll
            for (int r = 0; r < 4; ++r)
                ah[mh][mt * 4 + r] = sAh[mh * 64 + mt * 16 + kq * 4 + r];
    int bidx = p0 >> 11;   // sequence index (2048 positions per sequence)
#pragma unroll 1
    for (int pass = 0; pass < 8; ++pass) {
        const ushort_t* gB = wa_b + (size_t)(w * 16 + pass * 2) * 4096 + lane * 8;
        f32x4 acc[2][4][2];
        bf16x8 bfr[2][2];
#pragma unroll
        for (int nt = 0; nt < 2; ++nt)
            bfr[0][nt] = *(const bf16x8*)(gB + nt * 4096);
#pragma unroll
        for (int ks = 0; ks < 8; ++ks) {
            int cur = ks & 1, nxt = cur ^ 1;
            if (ks < 7) {
#pragma unroll
                for (int nt = 0; nt < 2; ++nt)
                    bfr[nxt][nt] = *(const bf16x8*)(gB + nt * 4096 + (ks + 1) * 512);
            }
#pragma unroll
            for (int mh = 0; mh < 2; ++mh) {
                bf16x8 a_[4];
#pragma unroll
                for (int mt = 0; mt < 4; ++mt)
                    a_[mt] = *(const bf16x8*)&sA[mh * 16384 +
                                                ((mt * 32 + ks * 4 + kq) * 16 + nl) * 8];
                if (ks == 0) {
                    f32x4 z4 = {0.f, 0.f, 0.f, 0.f};
#pragma unroll
                    for (int mt = 0; mt < 4; ++mt)
#pragma unroll
                        for (int nt = 0; nt < 2; ++nt)
                            acc[mh][mt][nt] = MFMA16(a_[mt], bfr[0][nt], z4);
                } else {
#pragma unroll
                    for (int mt = 0; mt < 4; ++mt)
#pragma unroll
                        for (int nt = 0; nt < 2; ++nt)
                            acc[mh][mt][nt] = MFMA16(a_[mt], bfr[cur][nt], acc[mh][mt][nt]);
                }
            }
        }
        // epilogue: leaky(acc+ba)*A_hat over both mh halves, reduce 128 m-rows,
        // one atomicAdd per (nt) per wave
#pragma unroll
        for (int nt = 0; nt < 2; ++nt) {
            int ng = w * 256 + pass * 32 + nt * 16 + nl;
            float ban = ba[ng];
            float s = 0.f;
#pragma unroll
            for (int mh = 0; mh < 2; ++mh)
#pragma unroll
                for (int mt = 0; mt < 4; ++mt)
#pragma unroll
                    for (int r = 0; r < 4; ++r) {
                        float v = acc[mh][mt][nt][r] + ban;
                        v = fmaxf(v, 0.2f * v);
                        s += v * ah[mh][mt * 4 + r];
                    }
            s += __shfl_xor(s, 16, 64);
            s += __shfl_xor(s, 32, 64);
            if (kq == 0) atomicAdd(&u_i[bidx * 1024 + ng], s);
        }
    }
}

// ---------------- Fallback: the verified R1 fully-fused kernel (used only if
// the workspace is too small for ghi).
__global__ __launch_bounds__(256, 2) void k_fused_fb(
    const int* __restrict__ q_seq, const int* __restrict__ r_seq,
    const float* __restrict__ t_seq, const float* __restrict__ q_tab,
    const float* __restrict__ r_tab,
    const ushort_t* __restrict__ ws1h, const ushort_t* __restrict__ ws1l,
    const float* __restrict__ consth, const float* __restrict__ Ws2,
    const float* __restrict__ bs2, const float* __restrict__ mask,
    const ushort_t* __restrict__ wa_b, const float* __restrict__ ba,
    float* __restrict__ out_ahat, float* __restrict__ u_i) {
    __shared__ __align__(16) ushort_t sAhi[16384];
    __shared__ __align__(16) ushort_t sAlo[16384];
    __shared__ float sdiv[128];
    __shared__ float sLogit[64];
    __shared__ float sAh[64];
    int tid = threadIdx.x;
    if (tid < 128) sdiv[tid] = __expf((float)tid * -0.07195578415606394f);
    if (tid < 64) sLogit[tid] = 0.0f;
    int w = tid >> 6, lane = tid & 63;
    int pl = lane & 15, kq = lane >> 4;
    int nl = pl;
    int p0 = blockIdx.x * 64;
    int p = p0 + w * 16 + pl;
    int qv = q_seq[p];
    int rr = r_seq[p];
    float tt = t_seq[p];
    const float* grow = q_tab + (size_t)qv * 256;
    const float* rrow = r_tab + (size_t)rr * 256;
    __syncthreads();
#pragma unroll
    for (int it = 0; it < 8; ++it) {
        int kc = it * 4 + kq;
        int k0 = kc * 8;
        float4 qa = *(const float4*)(grow + kc * 8);
        float4 qb = *(const float4*)(grow + kc * 8 + 4);
        float4 ra = *(const float4*)(rrow + kc * 8);
        float4 rb = *(const float4*)(rrow + kc * 8 + 4);
        float v[8] = {qa.x + ra.x, qa.y + ra.y, qa.z + ra.z, qa.w + ra.w,
                      qb.x + rb.x, qb.y + rb.y, qb.z + rb.z, qb.w + rb.w};
        bool iscos = (kc >= 16);
#pragma unroll
        for (int j = 0; j < 8; ++j) {
            float ang = tt * sdiv[(k0 + j) & 127];
            v[j] += iscos ? __cosf(ang) : __sinf(ang);
        }
        ushort_t hs[8], ls[8];
#pragma unroll
        for (int j = 0; j < 8; ++j) {
            ushort_t h = f2bf(v[j]);
            hs[j] = h;
            ls[j] = (ushort_t)(__float_as_uint(v[j] - bf2f(h)) >> 16);
        }
        uint4 hv, lv;
        hv.x = hs[0] | ((uint_t)hs[1] << 16); hv.y = hs[2] | ((uint_t)hs[3] << 16);
        hv.z = hs[4] | ((uint_t)hs[5] << 16); hv.w = hs[6] | ((uint_t)hs[7] << 16);
        lv.x = ls[0] | ((uint_t)ls[1] << 16); lv.y = ls[2] | ((uint_t)ls[3] << 16);
        lv.z = ls[4] | ((uint_t)ls[5] << 16); lv.w = ls[6] | ((uint_t)ls[7] << 16);
        int loff = ((w * 32 + kc) * 16 + pl) * 8;
        *(uint4*)(sAhi + loff) = hv;
        *(uint4*)(sAlo + loff) = lv;
    }
    __syncthreads();
    {
        f32x4 acc[4][2];
        f32x4 z4 = {0.f, 0.f, 0.f, 0.f};
#pragma unroll
        for (int mt = 0; mt < 4; ++mt)
#pragma unroll
            for (int nt = 0; nt < 2; ++nt) acc[mt][nt] = z4;
        bf16x8 bh[2][2], bl[2][2];
#pragma unroll
        for (int nt = 0; nt < 2; ++nt) {
            int off = (((w * 2 + nt) * 32 + kq) * 16 + nl) * 8;
            bh[0][nt] = *(const bf16x8*)(ws1h + off);
            bl[0][nt] = *(const bf16x8*)(ws1l + off);
        }
#pragma unroll
        for (int ks = 0; ks < 8; ++ks) {
            int cur = ks & 1, nxt = cur ^ 1;
            if (ks < 7) {
#pragma unroll
                for (int nt = 0; nt < 2; ++nt) {
                    int off = (((w * 2 + nt) * 32 + (ks + 1) * 4 + kq) * 16 + nl) * 8;
                    bh[nxt][nt] = *(const bf16x8*)(ws1h + off);
                    bl[nxt][nt] = *(const bf16x8*)(ws1l + off);
                }
            }
            bf16x8 ahi[4], alo[4];
#pragma unroll
            for (int mt = 0; mt < 4; ++mt) {
                int off = ((mt * 32 + ks * 4 + kq) * 16 + nl) * 8;
                ahi[mt] = *(const bf16x8*)&sAhi[off];
                alo[mt] = *(const bf16x8*)&sAlo[off];
            }
#pragma unroll
            for (int mt = 0; mt < 4; ++mt)
#pragma unroll
                for (int nt = 0; nt < 2; ++nt) {
                    acc[mt][nt] = MFMA16(ahi[mt], bh[cur][nt], acc[mt][nt]);
                    acc[mt][nt] = MFMA16(alo[mt], bh[cur][nt], acc[mt][nt]);
                    acc[mt][nt] = MFMA16(ahi[mt], bl[cur][nt], acc[mt][nt]);
                }
        }
        float ps[4][4];
#pragma unroll
        for (int mt = 0; mt < 4; ++mt)
#pragma unroll
            for (int r = 0; r < 4; ++r) ps[mt][r] = 0.f;
#pragma unroll
        for (int nt = 0; nt < 2; ++nt) {
            int ng = w * 32 + nt * 16 + nl;
            float chv = consth[ng], w2 = Ws2[ng];
#pragma unroll
            for (int mt = 0; mt < 4; ++mt)
#pragma unroll
                for (int r = 0; r < 4; ++r) {
                    float v = acc[mt][nt][r] + chv;
                    v = fmaxf(v, 0.2f * v);
                    ps[mt][r] += v * w2;
                }
        }
#pragma unroll
        for (int mt = 0; mt < 4; ++mt)
#pragma unroll
            for (int r = 0; r < 4; ++r) {
                float x = ps[mt][r];
                x += __shfl_xor(x, 1, 64);
                x += __shfl_xor(x, 2, 64);
                x += __shfl_xor(x, 4, 64);
                x += __shfl_xor(x, 8, 64);
                ps[mt][r] = x;
            }
        if (nl == 0) {
#pragma unroll
            for (int mt = 0; mt < 4; ++mt)
#pragma unroll
                for (int r = 0; r < 4; ++r)
                    atomicAdd(&sLogit[mt * 16 + kq * 4 + r], ps[mt][r]);
        }
    }
    __syncthreads();
    if (tid < 64) {
        int pp = p0 + tid;
        float lg = sLogit[tid] + bs2[0];
        float y = lg * 100.0f;
        y = fminf(fmaxf(y, -60.f), 60.f);
        float a = 1.0f / (1.0f + expf(-y));
        float av = a * mask[pp];
        out_ahat[pp] = av;
        sAh[tid] = av;
    }
    __syncthreads();
    {
        float ah[16];
#pragma unroll
        for (int mt = 0; mt < 4; ++mt)
#pragma unroll
            for (int r = 0; r < 4; ++r) ah[mt * 4 + r] = sAh[mt * 16 + kq * 4 + r];
        int bidx = p0 >> 11;
#pragma unroll 1
        for (int nblk = 0; nblk < 4; ++nblk) {
#pragma unroll 1
            for (int hf = 0; hf < 2; ++hf) {
                const ushort_t* gB = wa_b + (size_t)(w * 16 + nblk * 4 + hf * 2) * 4096 + lane * 8;
                f32x4 acc[4][2];
                bf16x8 bfr[2][2];
#pragma unroll
                for (int nt = 0; nt < 2; ++nt)
                    bfr[0][nt] = *(const bf16x8*)(gB + nt * 4096);
#pragma unroll
                for (int ks = 0; ks < 8; ++ks) {
                    int cur = ks & 1, nxt = cur ^ 1;
                    if (ks < 7) {
#pragma unroll
                        for (int nt = 0; nt < 2; ++nt)
                            bfr[nxt][nt] = *(const bf16x8*)(gB + nt * 4096 + (ks + 1) * 512);
                    }
                    bf16x8 a_[4];
#pragma unroll
                    for (int mt = 0; mt < 4; ++mt)
                        a_[mt] = *(const bf16x8*)&sAhi[((mt * 32 + ks * 4 + kq) * 16 + nl) * 8];
                    if (ks == 0) {
                        f32x4 z4 = {0.f, 0.f, 0.f, 0.f};
#pragma unroll
                        for (int mt = 0; mt < 4; ++mt)
#pragma unroll
                            for (int nt = 0; nt < 2; ++nt)
                                acc[mt][nt] = MFMA16(a_[mt], bfr[0][nt], z4);
                    } else {
#pragma unroll
                        for (int mt = 0; mt < 4; ++mt)
#pragma unroll
                            for (int nt = 0; nt < 2; ++nt)
                                acc[mt][nt] = MFMA16(a_[mt], bfr[cur][nt], acc[mt][nt]);
                    }
                }
#pragma unroll
                for (int nt = 0; nt < 2; ++nt) {
                    int ng = w * 256 + nblk * 64 + (hf * 2 + nt) * 16 + nl;
                    float ban = ba[ng];
                    float s = 0.f;
#pragma unroll
                    for (int mt = 0; mt < 4; ++mt)
#pragma unroll
                        for (int r = 0; r < 4; ++r) {
                            float v = acc[mt][nt][r] + ban;
                            v = fmaxf(v, 0.2f * v);
                            s += v * ah[mt * 4 + r];
                        }
                    s += __shfl_xor(s, 16, 64);
                    s += __shfl_xor(s, 32, 64);
                    if (kq == 0) atomicAdd(&u_i[bidx * 1024 + ng], s);
                }
            }
        }
    }
}

extern "C" void kernel_launch(void* const* d_in, const int* in_sizes, int n_in,
                              void* d_out, int out_size, void* d_ws, size_t ws_size,
                              hipStream_t stream) {
    const int* q_seq = (const int*)d_in[0];
    const int* r_seq = (const int*)d_in[1];
    const float* t_seq = (const float*)d_in[2];
    const float* mask = (const float*)d_in[3];
    const float* q_tab = (const float*)d_in[4];
    const float* r_tab = (const float*)d_in[5];
    const float* virt = (const float*)d_in[6];
    const float* Ws1 = (const float*)d_in[7];
    const float* bs1 = (const float*)d_in[8];
    const float* Ws2 = (const float*)d_in[9];
    const float* bs2 = (const float*)d_in[10];
    const float* Wa = (const float*)d_in[11];
    const float* ba = (const float*)d_in[12];
    float* out = (float*)d_out;

    // ws layout
    ushort_t* wa_b = (ushort_t*)d_ws;            // 1024*256 bf16 blocked (512 KB)
    ushort_t* ws1h = wa_b + 262144;              // 128*256 bf16 blocked (64 KB)
    ushort_t* ws1l = ws1h + 32768;               // 64 KB
    float* ch = (float*)(ws1l + 32768);          // 128 f32 (512 B)
    ushort_t* ghi = (ushort_t*)(ch + 128);       // 131072*256 bf16 blocked (64 MB)
    const size_t need = 524288 + 65536 + 65536 + 512 + 67108864;

    hipLaunchKernelGGL(k_prep, dim3(209), dim3(256), 0, stream,
                       Ws1, bs1, virt, Wa, ch, wa_b, ws1h, ws1l, out);
    if (ws_size >= need) {
        hipLaunchKernelGGL(k_embed, dim3(2048), dim3(256), 0, stream,
                           q_seq, r_seq, t_seq, q_tab, r_tab, ws1h, ws1l, ch, Ws2,
                           bs2, mask, out + 65536, ghi);
        hipLaunchKernelGGL(k_wa, dim3(1024), dim3(256), 0, stream,
                           ghi, out + 65536, wa_b, ba, out);
    } else {
        hipLaunchKernelGGL(k_fused_fb, dim3(2048), dim3(256), 0, stream,
                           q_seq, r_seq, t_seq, q_tab, r_tab, ws1h, ws1l, ch, Ws2,
                           bs2, mask, wa_b, ba, out + 65536, out);
    }
}

// Round 10
// 240.458 us; speedup vs baseline: 1.6780x; 1.6780x over previous
//
#include <hip/hip_runtime.h>

typedef unsigned short ushort_t;
typedef unsigned int uint_t;

typedef short bf16x8 __attribute__((ext_vector_type(8)));
typedef float f32x4 __attribute__((ext_vector_type(4)));

#define MFMA16(a, b, c) __builtin_amdgcn_mfma_f32_16x16x32_bf16(a, b, c, 0, 0, 0)

__device__ __forceinline__ ushort_t f2bf(float f) {
    uint_t u = __float_as_uint(f);
    u += 0x7fffu + ((u >> 16) & 1u);   // RNE
    return (ushort_t)(u >> 16);
}
__device__ __forceinline__ float bf2f(ushort_t h) {
    return __uint_as_float(((uint_t)h) << 16);
}

// ---------------- K0: fused prep.
// blocks 0..7:    const_h, WAVE-PARALLEL (R10: was a 128-deep serial scalar-load
//                 chain on cold HBM ~900cy/load ≈ 50-90 µs; now 4 rows/wave,
//                 64-lane float4 dot + butterfly reduce ≈ 1-2 µs)
// blocks 8..135:  Wa -> bf16 blocked
// blocks 136..151: Ws1[:, :256] -> bf16 hi/lo blocked
// blocks 152..215: zero u_i
// blocked flat (in 8-elem units): ((row/16)*32 + k/8)*16 + row%16
__global__ void k_prep(const float* __restrict__ Ws1, const float* __restrict__ bs1,
                       const float* __restrict__ virt, const float* __restrict__ Wa,
                       float* __restrict__ consth, ushort_t* __restrict__ wa_b,
                       ushort_t* __restrict__ ws1h, ushort_t* __restrict__ ws1l,
                       float* __restrict__ u_i) {
    int b = blockIdx.x;
    if (b < 8) {
        // const_h: 16 rows per block, 4 rows per wave, full-wave dot per row
        int w = threadIdx.x >> 6, lane = threadIdx.x & 63;
#pragma unroll
        for (int i = 0; i < 4; ++i) {
            int row = b * 16 + w * 4 + i;
            const float* rp = Ws1 + row * 512 + 256;
            float4 v = *(const float4*)(rp + lane * 4);
            float4 vv = *(const float4*)(virt + lane * 4);
            float s = v.x * vv.x + v.y * vv.y + v.z * vv.z + v.w * vv.w;
            s += __shfl_xor(s, 1, 64);
            s += __shfl_xor(s, 2, 64);
            s += __shfl_xor(s, 4, 64);
            s += __shfl_xor(s, 8, 64);
            s += __shfl_xor(s, 16, 64);
            s += __shfl_xor(s, 32, 64);
            if (lane == 0) consth[row] = bs1[row] + s;
        }
        return;
    }
    if (b >= 152) {
        // zero u_i: 64 blocks x 256 threads x 4 floats = 65536
        int t = (b - 152) * 1024 + threadIdx.x * 4;
        float4 z = {0.f, 0.f, 0.f, 0.f};
        *(float4*)(u_i + t) = z;
        return;
    }
    const float* src;
    int src_stride, tid;
    ushort_t *dhi, *dlo;
    if (b <= 135) {
        tid = (b - 8) * 256 + threadIdx.x;   // 1024 rows * 32 = 32768 tids
        src = Wa; src_stride = 256; dhi = wa_b; dlo = nullptr;
    } else {
        tid = (b - 136) * 256 + threadIdx.x; // 128 rows * 32 = 4096 tids
        src = Ws1; src_stride = 512; dhi = ws1h; dlo = ws1l;
    }
    int pl = tid & 15, kc = (tid >> 4) & 31, pt = tid >> 9;
    int row = pt * 16 + pl;
    const float* s = src + (size_t)row * src_stride + kc * 8;
    ushort_t hs[8], ls[8];
#pragma unroll
    for (int j = 0; j < 8; ++j) {
        float v = s[j];
        ushort_t h = f2bf(v);
        hs[j] = h;
        ls[j] = f2bf(v - bf2f(h));
    }
    uint4 hv;
    hv.x = hs[0] | ((uint_t)hs[1] << 16); hv.y = hs[2] | ((uint_t)hs[3] << 16);
    hv.z = hs[4] | ((uint_t)hs[5] << 16); hv.w = hs[6] | ((uint_t)hs[7] << 16);
    *(uint4*)(dhi + (size_t)tid * 8) = hv;
    if (dlo) {
        uint4 lv;
        lv.x = ls[0] | ((uint_t)ls[1] << 16); lv.y = ls[2] | ((uint_t)ls[3] << 16);
        lv.z = ls[4] | ((uint_t)ls[5] << 16); lv.w = ls[6] | ((uint_t)ls[7] << 16);
        *(uint4*)(dlo + (size_t)tid * 8) = lv;
    }
}

// ---------------- K1a: embed (gather+trig) + split-bf16 struct head + sigmoid.
// Writes hi-fragments (blocked, 32 KB/block contiguous) to ghi for K1b, and A_hat.
// (unchanged from R4 — verified)
__global__ __launch_bounds__(256, 2) void k_embed(
    const int* __restrict__ q_seq, const int* __restrict__ r_seq,
    const float* __restrict__ t_seq, const float* __restrict__ q_tab,
    const float* __restrict__ r_tab,
    const ushort_t* __restrict__ ws1h, const ushort_t* __restrict__ ws1l,
    const float* __restrict__ consth, const float* __restrict__ Ws2,
    const float* __restrict__ bs2, const float* __restrict__ mask,
    float* __restrict__ out_ahat, ushort_t* __restrict__ ghi) {
    __shared__ __align__(16) ushort_t sAhi[16384];   // 64 pos x 256 k (hi), 32 KB
    __shared__ __align__(16) ushort_t sAlo[8192];    // 64 pos x 128 k (lo half), 16 KB
    __shared__ float sdiv[128];
    __shared__ float sLogit[64];
    int tid = threadIdx.x;
    if (tid < 128) sdiv[tid] = __expf((float)tid * -0.07195578415606394f); // -ln(10000)/128
    if (tid < 64) sLogit[tid] = 0.0f;
    int w = tid >> 6, lane = tid & 63;
    int pl = lane & 15, kq = lane >> 4;
    int nl = pl;
    int p0 = blockIdx.x * 64;
    int p = p0 + w * 16 + pl;
    int qv = q_seq[p];          // lanes with same pl share qv (same p)
    int rr = r_seq[p];
    float tt = t_seq[p];
    const float* grow = q_tab + (size_t)qv * 256;
    const float* rrow = r_tab + (size_t)rr * 256;
    uint4* gdst = (uint4*)(ghi + (size_t)blockIdx.x * 16384);
    __syncthreads();  // sdiv + sLogit ready
    // ---- gather + trig -> fragments to LDS (MFMA A-layout) + hi copy to global
    uint4 lo_hold[4];
#pragma unroll
    for (int it = 0; it < 8; ++it) {
        int kc = it * 4 + kq;
        int k0 = kc * 8;
        float4 qa = *(const float4*)(grow + kc * 8);
        float4 qb = *(const float4*)(grow + kc * 8 + 4);
        float4 ra = *(const float4*)(rrow + kc * 8);
        float4 rb = *(const float4*)(rrow + kc * 8 + 4);
        float v[8] = {qa.x + ra.x, qa.y + ra.y, qa.z + ra.z, qa.w + ra.w,
                      qb.x + rb.x, qb.y + rb.y, qb.z + rb.z, qb.w + rb.w};
        bool iscos = (kc >= 16);
#pragma unroll
        for (int j = 0; j < 8; ++j) {
            float ang = tt * sdiv[(k0 + j) & 127];
            v[j] += iscos ? __cosf(ang) : __sinf(ang);
        }
        ushort_t hs[8], ls[8];
#pragma unroll
        for (int j = 0; j < 8; ++j) {
            ushort_t h = f2bf(v[j]);
            hs[j] = h;
            ls[j] = (ushort_t)(__float_as_uint(v[j] - bf2f(h)) >> 16);
        }
        uint4 hv, lv;
        hv.x = hs[0] | ((uint_t)hs[1] << 16); hv.y = hs[2] | ((uint_t)hs[3] << 16);
        hv.z = hs[4] | ((uint_t)hs[5] << 16); hv.w = hs[6] | ((uint_t)hs[7] << 16);
        lv.x = ls[0] | ((uint_t)ls[1] << 16); lv.y = ls[2] | ((uint_t)ls[3] << 16);
        lv.z = ls[4] | ((uint_t)ls[5] << 16); lv.w = ls[6] | ((uint_t)ls[7] << 16);
        int unit = (w * 32 + kc) * 16 + pl;
        *(uint4*)(sAhi + unit * 8) = hv;
        gdst[unit] = hv;
        if (it < 4) {
            *(uint4*)(sAlo + ((w * 16 + kc) * 16 + pl) * 8) = lv;   // kc in 0..15
        } else {
            lo_hold[it - 4] = lv;
        }
    }
    __syncthreads();  // fragments visible block-wide
    // ---- struct head (split-bf16, 3 MFMAs), two k-phases over the halved sAlo
    {
        f32x4 acc[4][2];
        f32x4 z4 = {0.f, 0.f, 0.f, 0.f};
#pragma unroll
        for (int mt = 0; mt < 4; ++mt)
#pragma unroll
            for (int nt = 0; nt < 2; ++nt) acc[mt][nt] = z4;
#pragma unroll
        for (int ks = 0; ks < 8; ++ks) {
            if (ks == 4) {
                // swap in the second lo half (barrier: all phase-A sAlo reads done)
                __syncthreads();
#pragma unroll
                for (int it = 4; it < 8; ++it) {
                    int kc = it * 4 + kq;
                    *(uint4*)(sAlo + ((w * 16 + (kc - 16)) * 16 + pl) * 8) = lo_hold[it - 4];
                }
                __syncthreads();
            }
            bf16x8 bh[2], bl[2];
#pragma unroll
            for (int nt = 0; nt < 2; ++nt) {
                int off = (((w * 2 + nt) * 32 + ks * 4 + kq) * 16 + nl) * 8;
                bh[nt] = *(const bf16x8*)(ws1h + off);
                bl[nt] = *(const bf16x8*)(ws1l + off);
            }
#pragma unroll
            for (int mth = 0; mth < 2; ++mth) {
                bf16x8 ahi[2], alo[2];
#pragma unroll
                for (int mi = 0; mi < 2; ++mi) {
                    int mt = mth * 2 + mi;
                    ahi[mi] = *(const bf16x8*)&sAhi[((mt * 32 + ks * 4 + kq) * 16 + nl) * 8];
                    alo[mi] = *(const bf16x8*)&sAlo[((mt * 16 + (ks & 3) * 4 + kq) * 16 + nl) * 8];
                }
#pragma unroll
                for (int mi = 0; mi < 2; ++mi)
#pragma unroll
                    for (int nt = 0; nt < 2; ++nt) {
                        int mt = mth * 2 + mi;
                        acc[mt][nt] = MFMA16(ahi[mi], bh[nt], acc[mt][nt]);
                        acc[mt][nt] = MFMA16(alo[mi], bh[nt], acc[mt][nt]);
                        acc[mt][nt] = MFMA16(ahi[mi], bl[nt], acc[mt][nt]);
                    }
            }
        }
        // epilogue: hdn = leaky(acc + const_h); partial logits = hdn * Ws2
        float ps[4][4];
#pragma unroll
        for (int mt = 0; mt < 4; ++mt)
#pragma unroll
            for (int r = 0; r < 4; ++r) ps[mt][r] = 0.f;
#pragma unroll
        for (int nt = 0; nt < 2; ++nt) {
            int ng = w * 32 + nt * 16 + nl;
            float chv = consth[ng], w2 = Ws2[ng];
#pragma unroll
            for (int mt = 0; mt < 4; ++mt)
#pragma unroll
                for (int r = 0; r < 4; ++r) {
                    float v = acc[mt][nt][r] + chv;
                    v = fmaxf(v, 0.2f * v);
                    ps[mt][r] += v * w2;
                }
        }
#pragma unroll
        for (int mt = 0; mt < 4; ++mt)
#pragma unroll
            for (int r = 0; r < 4; ++r) {
                float x = ps[mt][r];
                x += __shfl_xor(x, 1, 64);
                x += __shfl_xor(x, 2, 64);
                x += __shfl_xor(x, 4, 64);
                x += __shfl_xor(x, 8, 64);
                ps[mt][r] = x;
            }
        if (nl == 0) {
#pragma unroll
            for (int mt = 0; mt < 4; ++mt)
#pragma unroll
                for (int r = 0; r < 4; ++r)
                    atomicAdd(&sLogit[mt * 16 + kq * 4 + r], ps[mt][r]);
        }
    }
    __syncthreads();
    if (tid < 64) {
        int pp = p0 + tid;
        float lg = sLogit[tid] + bs2[0];
        float y = lg * 100.0f;
        y = fminf(fmaxf(y, -60.f), 60.f);
        float a = 1.0f / (1.0f + expf(-y));
        out_ahat[pp] = a * mask[pp];
    }
}

// ---------------- K1b: Wa GEMM + aggregator — R4-EXACT revert (verified 88.6 µs,
// 112 VGPR, no spill). R5/R8/R9 all spilled trying to grow the working set
// (bfr[8] preload / min-waves=3 / M=128 dual-acc): this structure is the pinned
// optimum for this allocator. 64 pos/block, grid 2048, depth-1 parity B-dbuf.
__global__ __launch_bounds__(256, 2) void k_wa(
    const ushort_t* __restrict__ ghi, const float* __restrict__ out_ahat,
    const ushort_t* __restrict__ wa_b, const float* __restrict__ ba,
    float* __restrict__ u_i) {
    __shared__ __align__(16) ushort_t sA[16384];   // 64 pos x 256 k (hi), 32 KB
    __shared__ float sAh[64];
    int tid = threadIdx.x;
    int p0 = blockIdx.x * 64;
    // stage A-tile: 32 KB contiguous
    {
        const uint4* src = (const uint4*)(ghi + (size_t)blockIdx.x * 16384);
        uint4* dst = (uint4*)sA;
#pragma unroll
        for (int i = 0; i < 8; ++i) dst[tid + i * 256] = src[tid + i * 256];
    }
    if (tid < 64) sAh[tid] = out_ahat[p0 + tid];
    __syncthreads();
    int w = tid >> 6, lane = tid & 63;
    int pl = lane & 15, kq = lane >> 4;
    int nl = pl;
    float ah[16];
#pragma unroll
    for (int mt = 0; mt < 4; ++mt)
#pragma unroll
        for (int r = 0; r < 4; ++r) ah[mt * 4 + r] = sAh[mt * 16 + kq * 4 + r];
    int bidx = p0 >> 11;   // sequence index (2048 positions per sequence)
#pragma unroll 1
    for (int nblk = 0; nblk < 4; ++nblk) {
#pragma unroll 1
        for (int hf = 0; hf < 2; ++hf) {
            const ushort_t* gB = wa_b + (size_t)(w * 16 + nblk * 4 + hf * 2) * 4096 + lane * 8;
            f32x4 acc[4][2];
            bf16x8 bfr[2][2];
#pragma unroll
            for (int nt = 0; nt < 2; ++nt)
                bfr[0][nt] = *(const bf16x8*)(gB + nt * 4096);
#pragma unroll
            for (int ks = 0; ks < 8; ++ks) {
                int cur = ks & 1, nxt = cur ^ 1;
                if (ks < 7) {
#pragma unroll
                    for (int nt = 0; nt < 2; ++nt)
                        bfr[nxt][nt] = *(const bf16x8*)(gB + nt * 4096 + (ks + 1) * 512);
                }
                bf16x8 a_[4];
#pragma unroll
                for (int mt = 0; mt < 4; ++mt)
                    a_[mt] = *(const bf16x8*)&sA[((mt * 32 + ks * 4 + kq) * 16 + nl) * 8];
                if (ks == 0) {
                    f32x4 z4 = {0.f, 0.f, 0.f, 0.f};
#pragma unroll
                    for (int mt = 0; mt < 4; ++mt)
#pragma unroll
                        for (int nt = 0; nt < 2; ++nt)
                            acc[mt][nt] = MFMA16(a_[mt], bfr[0][nt], z4);
                } else {
#pragma unroll
                    for (int mt = 0; mt < 4; ++mt)
#pragma unroll
                        for (int nt = 0; nt < 2; ++nt)
                            acc[mt][nt] = MFMA16(a_[mt], bfr[cur][nt], acc[mt][nt]);
                }
            }
            // epilogue: leaky(acc+ba)*A_hat, reduce the 64 m-rows, atomicAdd u_i
#pragma unroll
            for (int nt = 0; nt < 2; ++nt) {
                int ng = w * 256 + nblk * 64 + (hf * 2 + nt) * 16 + nl;
                float ban = ba[ng];
                float s = 0.f;
#pragma unroll
                for (int mt = 0; mt < 4; ++mt)
#pragma unroll
                    for (int r = 0; r < 4; ++r) {
                        float v = acc[mt][nt][r] + ban;
                        v = fmaxf(v, 0.2f * v);
                        s += v * ah[mt * 4 + r];
                    }
                s += __shfl_xor(s, 16, 64);
                s += __shfl_xor(s, 32, 64);
                if (kq == 0) atomicAdd(&u_i[bidx * 1024 + ng], s);
            }
        }
    }
}

// ---------------- Fallback: the verified R1 fully-fused kernel (used only if
// the workspace is too small for ghi).
__global__ __launch_bounds__(256, 2) void k_fused_fb(
    const int* __restrict__ q_seq, const int* __restrict__ r_seq,
    const float* __restrict__ t_seq, const float* __restrict__ q_tab,
    const float* __restrict__ r_tab,
    const ushort_t* __restrict__ ws1h, const ushort_t* __restrict__ ws1l,
    const float* __restrict__ consth, const float* __restrict__ Ws2,
    const float* __restrict__ bs2, const float* __restrict__ mask,
    const ushort_t* __restrict__ wa_b, const float* __restrict__ ba,
    float* __restrict__ out_ahat, float* __restrict__ u_i) {
    __shared__ __align__(16) ushort_t sAhi[16384];
    __shared__ __align__(16) ushort_t sAlo[16384];
    __shared__ float sdiv[128];
    __shared__ float sLogit[64];
    __shared__ float sAh[64];
    int tid = threadIdx.x;
    if (tid < 128) sdiv[tid] = __expf((float)tid * -0.07195578415606394f);
    if (tid < 64) sLogit[tid] = 0.0f;
    int w = tid >> 6, lane = tid & 63;
    int pl = lane & 15, kq = lane >> 4;
    int nl = pl;
    int p0 = blockIdx.x * 64;
    int p = p0 + w * 16 + pl;
    int qv = q_seq[p];
    int rr = r_seq[p];
    float tt = t_seq[p];
    const float* grow = q_tab + (size_t)qv * 256;
    const float* rrow = r_tab + (size_t)rr * 256;
    __syncthreads();
#pragma unroll
    for (int it = 0; it < 8; ++it) {
        int kc = it * 4 + kq;
        int k0 = kc * 8;
        float4 qa = *(const float4*)(grow + kc * 8);
        float4 qb = *(const float4*)(grow + kc * 8 + 4);
        float4 ra = *(const float4*)(rrow + kc * 8);
        float4 rb = *(const float4*)(rrow + kc * 8 + 4);
        float v[8] = {qa.x + ra.x, qa.y + ra.y, qa.z + ra.z, qa.w + ra.w,
                      qb.x + rb.x, qb.y + rb.y, qb.z + rb.z, qb.w + rb.w};
        bool iscos = (kc >= 16);
#pragma unroll
        for (int j = 0; j < 8; ++j) {
            float ang = tt * sdiv[(k0 + j) & 127];
            v[j] += iscos ? __cosf(ang) : __sinf(ang);
        }
        ushort_t hs[8], ls[8];
#pragma unroll
        for (int j = 0; j < 8; ++j) {
            ushort_t h = f2bf(v[j]);
            hs[j] = h;
            ls[j] = (ushort_t)(__float_as_uint(v[j] - bf2f(h)) >> 16);
        }
        uint4 hv, lv;
        hv.x = hs[0] | ((uint_t)hs[1] << 16); hv.y = hs[2] | ((uint_t)hs[3] << 16);
        hv.z = hs[4] | ((uint_t)hs[5] << 16); hv.w = hs[6] | ((uint_t)hs[7] << 16);
        lv.x = ls[0] | ((uint_t)ls[1] << 16); lv.y = ls[2] | ((uint_t)ls[3] << 16);
        lv.z = ls[4] | ((uint_t)ls[5] << 16); lv.w = ls[6] | ((uint_t)ls[7] << 16);
        int loff = ((w * 32 + kc) * 16 + pl) * 8;
        *(uint4*)(sAhi + loff) = hv;
        *(uint4*)(sAlo + loff) = lv;
    }
    __syncthreads();
    {
        f32x4 acc[4][2];
        f32x4 z4 = {0.f, 0.f, 0.f, 0.f};
#pragma unroll
        for (int mt = 0; mt < 4; ++mt)
#pragma unroll
            for (int nt = 0; nt < 2; ++nt) acc[mt][nt] = z4;
        bf16x8 bh[2][2], bl[2][2];
#pragma unroll
        for (int nt = 0; nt < 2; ++nt) {
            int off = (((w * 2 + nt) * 32 + kq) * 16 + nl) * 8;
            bh[0][nt] = *(const bf16x8*)(ws1h + off);
            bl[0][nt] = *(const bf16x8*)(ws1l + off);
        }
#pragma unroll
        for (int ks = 0; ks < 8; ++ks) {
            int cur = ks & 1, nxt = cur ^ 1;
            if (ks < 7) {
#pragma unroll
                for (int nt = 0; nt < 2; ++nt) {
                    int off = (((w * 2 + nt) * 32 + (ks + 1) * 4 + kq) * 16 + nl) * 8;
                    bh[nxt][nt] = *(const bf16x8*)(ws1h + off);
                    bl[nxt][nt] = *(const bf16x8*)(ws1l + off);
                }
            }
            bf16x8 ahi[4], alo[4];
#pragma unroll
            for (int mt = 0; mt < 4; ++mt) {
                int off = ((mt * 32 + ks * 4 + kq) * 16 + nl) * 8;
                ahi[mt] = *(const bf16x8*)&sAhi[off];
                alo[mt] = *(const bf16x8*)&sAlo[off];
            }
#pragma unroll
            for (int mt = 0; mt < 4; ++mt)
#pragma unroll
                for (int nt = 0; nt < 2; ++nt) {
                    acc[mt][nt] = MFMA16(ahi[mt], bh[cur][nt], acc[mt][nt]);
                    acc[mt][nt] = MFMA16(alo[mt], bh[cur][nt], acc[mt][nt]);
                    acc[mt][nt] = MFMA16(ahi[mt], bl[cur][nt], acc[mt][nt]);
                }
        }
        float ps[4][4];
#pragma unroll
        for (int mt = 0; mt < 4; ++mt)
#pragma unroll
            for (int r = 0; r < 4; ++r) ps[mt][r] = 0.f;
#pragma unroll
        for (int nt = 0; nt < 2; ++nt) {
            int ng = w * 32 + nt * 16 + nl;
            float chv = consth[ng], w2 = Ws2[ng];
#pragma unroll
            for (int mt = 0; mt < 4; ++mt)
#pragma unroll
                for (int r = 0; r < 4; ++r) {
                    float v = acc[mt][nt][r] + chv;
                    v = fmaxf(v, 0.2f * v);
                    ps[mt][r] += v * w2;
                }
        }
#pragma unroll
        for (int mt = 0; mt < 4; ++mt)
#pragma unroll
            for (int r = 0; r < 4; ++r) {
                float x = ps[mt][r];
                x += __shfl_xor(x, 1, 64);
                x += __shfl_xor(x, 2, 64);
                x += __shfl_xor(x, 4, 64);
                x += __shfl_xor(x, 8, 64);
                ps[mt][r] = x;
            }
        if (nl == 0) {
#pragma unroll
            for (int mt = 0; mt < 4; ++mt)
#pragma unroll
                for (int r = 0; r < 4; ++r)
                    atomicAdd(&sLogit[mt * 16 + kq * 4 + r], ps[mt][r]);
        }
    }
    __syncthreads();
    if (tid < 64) {
        int pp = p0 + tid;
        float lg = sLogit[tid] + bs2[0];
        float y = lg * 100.0f;
        y = fminf(fmaxf(y, -60.f), 60.f);
        float a = 1.0f / (1.0f + expf(-y));
        float av = a * mask[pp];
        out_ahat[pp] = av;
        sAh[tid] = av;
    }
    __syncthreads();
    {
        float ah[16];
#pragma unroll
        for (int mt = 0; mt < 4; ++mt)
#pragma unroll
            for (int r = 0; r < 4; ++r) ah[mt * 4 + r] = sAh[mt * 16 + kq * 4 + r];
        int bidx = p0 >> 11;
#pragma unroll 1
        for (int nblk = 0; nblk < 4; ++nblk) {
#pragma unroll 1
            for (int hf = 0; hf < 2; ++hf) {
                const ushort_t* gB = wa_b + (size_t)(w * 16 + nblk * 4 + hf * 2) * 4096 + lane * 8;
                f32x4 acc[4][2];
                bf16x8 bfr[2][2];
#pragma unroll
                for (int nt = 0; nt < 2; ++nt)
                    bfr[0][nt] = *(const bf16x8*)(gB + nt * 4096);
#pragma unroll
                for (int ks = 0; ks < 8; ++ks) {
                    int cur = ks & 1, nxt = cur ^ 1;
                    if (ks < 7) {
#pragma unroll
                        for (int nt = 0; nt < 2; ++nt)
                            bfr[nxt][nt] = *(const bf16x8*)(gB + nt * 4096 + (ks + 1) * 512);
                    }
                    bf16x8 a_[4];
#pragma unroll
                    for (int mt = 0; mt < 4; ++mt)
                        a_[mt] = *(const bf16x8*)&sAhi[((mt * 32 + ks * 4 + kq) * 16 + nl) * 8];
                    if (ks == 0) {
                        f32x4 z4 = {0.f, 0.f, 0.f, 0.f};
#pragma unroll
                        for (int mt = 0; mt < 4; ++mt)
#pragma unroll
                            for (int nt = 0; nt < 2; ++nt)
                                acc[mt][nt] = MFMA16(a_[mt], bfr[0][nt], z4);
                    } else {
#pragma unroll
                        for (int mt = 0; mt < 4; ++mt)
#pragma unroll
                            for (int nt = 0; nt < 2; ++nt)
                                acc[mt][nt] = MFMA16(a_[mt], bfr[cur][nt], acc[mt][nt]);
                    }
                }
#pragma unroll
                for (int nt = 0; nt < 2; ++nt) {
                    int ng = w * 256 + nblk * 64 + (hf * 2 + nt) * 16 + nl;
                    float ban = ba[ng];
                    float s = 0.f;
#pragma unroll
                    for (int mt = 0; mt < 4; ++mt)
#pragma unroll
                        for (int r = 0; r < 4; ++r) {
                            float v = acc[mt][nt][r] + ban;
                            v = fmaxf(v, 0.2f * v);
                            s += v * ah[mt * 4 + r];
                        }
                    s += __shfl_xor(s, 16, 64);
                    s += __shfl_xor(s, 32, 64);
                    if (kq == 0) atomicAdd(&u_i[bidx * 1024 + ng], s);
                }
            }
        }
    }
}

extern "C" void kernel_launch(void* const* d_in, const int* in_sizes, int n_in,
                              void* d_out, int out_size, void* d_ws, size_t ws_size,
                              hipStream_t stream) {
    const int* q_seq = (const int*)d_in[0];
    const int* r_seq = (const int*)d_in[1];
    const float* t_seq = (const float*)d_in[2];
    const float* mask = (const float*)d_in[3];
    const float* q_tab = (const float*)d_in[4];
    const float* r_tab = (const float*)d_in[5];
    const float* virt = (const float*)d_in[6];
    const float* Ws1 = (const float*)d_in[7];
    const float* bs1 = (const float*)d_in[8];
    const float* Ws2 = (const float*)d_in[9];
    const float* bs2 = (const float*)d_in[10];
    const float* Wa = (const float*)d_in[11];
    const float* ba = (const float*)d_in[12];
    float* out = (float*)d_out;

    // ws layout
    ushort_t* wa_b = (ushort_t*)d_ws;            // 1024*256 bf16 blocked (512 KB)
    ushort_t* ws1h = wa_b + 262144;              // 128*256 bf16 blocked (64 KB)
    ushort_t* ws1l = ws1h + 32768;               // 64 KB
    float* ch = (float*)(ws1l + 32768);          // 128 f32 (512 B)
    ushort_t* ghi = (ushort_t*)(ch + 128);       // 131072*256 bf16 blocked (64 MB)
    const size_t need = 524288 + 65536 + 65536 + 512 + 67108864;

    hipLaunchKernelGGL(k_prep, dim3(216), dim3(256), 0, stream,
                       Ws1, bs1, virt, Wa, ch, wa_b, ws1h, ws1l, out);
    if (ws_size >= need) {
        hipLaunchKernelGGL(k_embed, dim3(2048), dim3(256), 0, stream,
                           q_seq, r_seq, t_seq, q_tab, r_tab, ws1h, ws1l, ch, Ws2,
                           bs2, mask, out + 65536, ghi);
        hipLaunchKernelGGL(k_wa, dim3(2048), dim3(256), 0, stream,
                           ghi, out + 65536, wa_b, ba, out);
    } else {
        hipLaunchKernelGGL(k_fused_fb, dim3(2048), dim3(256), 0, stream,
                           q_seq, r_seq, t_seq, q_tab, r_tab, ws1h, ws1l, ch, Ws2,
                           bs2, mask, wa_b, ba, out + 65536, out);
    }
}